// Round 1
// baseline (1031.395 us; speedup 1.0000x reference)
//
#include <hip/hip_runtime.h>
#include <hip/hip_bf16.h>

#define F_IN 512
#define HID 16
#define NCLS 64

// ---------------------------------------------------------------------------
// K1: h0 = relu(x @ W1 + b1), inv0 = 1/max(||h0||,eps)
// One wave per row. W1 fragment register-resident: lane l owns k = l*8..l*8+7.
// ---------------------------------------------------------------------------
__global__ __launch_bounds__(256) void gemm1_kernel(
    const float* __restrict__ x, const float* __restrict__ W1,
    const float* __restrict__ b1, float* __restrict__ h0,
    float* __restrict__ inv0, int N, int totalWaves)
{
    int wid  = (blockIdx.x * blockDim.x + threadIdx.x) >> 6;
    int lane = threadIdx.x & 63;

    // Load W1 fragment: w[kk][jj] = W1[(lane*8+kk)][jj*4..jj*4+3]
    float4 w[8][4];
#pragma unroll
    for (int kk = 0; kk < 8; ++kk) {
        const float4* wp = (const float4*)(W1 + (lane * 8 + kk) * HID);
#pragma unroll
        for (int jj = 0; jj < 4; ++jj) w[kk][jj] = wp[jj];
    }

    for (int row = wid; row < N; row += totalWaves) {
        const float4* xp = (const float4*)(x + (size_t)row * F_IN + lane * 8);
        float4 xa = xp[0], xb = xp[1];
        float xs[8] = {xa.x, xa.y, xa.z, xa.w, xb.x, xb.y, xb.z, xb.w};
        float4 acc[4];
#pragma unroll
        for (int jj = 0; jj < 4; ++jj) acc[jj] = make_float4(0.f, 0.f, 0.f, 0.f);

#pragma unroll
        for (int kk = 0; kk < 8; ++kk) {
            float xv = xs[kk];
#pragma unroll
            for (int jj = 0; jj < 4; ++jj) {
                acc[jj].x += xv * w[kk][jj].x;
                acc[jj].y += xv * w[kk][jj].y;
                acc[jj].z += xv * w[kk][jj].z;
                acc[jj].w += xv * w[kk][jj].w;
            }
        }
        // Butterfly reduce across 64 lanes (16 floats)
        for (int off = 32; off > 0; off >>= 1) {
#pragma unroll
            for (int jj = 0; jj < 4; ++jj) {
                acc[jj].x += __shfl_xor(acc[jj].x, off);
                acc[jj].y += __shfl_xor(acc[jj].y, off);
                acc[jj].z += __shfl_xor(acc[jj].z, off);
                acc[jj].w += __shfl_xor(acc[jj].w, off);
            }
        }
        if (lane == 0) {
            float vals[16] = {acc[0].x, acc[0].y, acc[0].z, acc[0].w,
                              acc[1].x, acc[1].y, acc[1].z, acc[1].w,
                              acc[2].x, acc[2].y, acc[2].z, acc[2].w,
                              acc[3].x, acc[3].y, acc[3].z, acc[3].w};
            float ss = 0.f;
            float4 o[4];
            float* of = (float*)o;
#pragma unroll
            for (int j = 0; j < 16; ++j) {
                float v = fmaxf(vals[j] + b1[j], 0.f);
                of[j] = v;
                ss += v * v;
            }
            float4* hp = (float4*)(h0 + (size_t)row * HID);
#pragma unroll
            for (int jj = 0; jj < 4; ++jj) hp[jj] = o[jj];
            inv0[row] = 1.f / fmaxf(sqrtf(ss), 1e-12f);
        }
    }
}

// ---------------------------------------------------------------------------
// CSR build over virtual edges i in [0, E+N): i<E -> (src[i],dst[i]); else self loop
// ---------------------------------------------------------------------------
__global__ void count_kernel(const int* __restrict__ dst, int E, int N,
                             int* __restrict__ counts)
{
    int i = blockIdx.x * blockDim.x + threadIdx.x;
    if (i >= E + N) return;
    int d = (i < E) ? dst[i] : (i - E);
    atomicAdd(&counts[d], 1);
}

__global__ void scanA_kernel(const int* __restrict__ counts, int N,
                             int* __restrict__ bsums)
{
    __shared__ int red[256];
    int t = threadIdx.x;
    int base = blockIdx.x * 1024 + t * 4;
    int sum = 0;
#pragma unroll
    for (int k = 0; k < 4; ++k) {
        int idx = base + k;
        if (idx < N) sum += counts[idx];
    }
    red[t] = sum;
    __syncthreads();
    for (int off = 128; off > 0; off >>= 1) {
        if (t < off) red[t] += red[t + off];
        __syncthreads();
    }
    if (t == 0) bsums[blockIdx.x] = red[0];
}

__global__ void scanB_kernel(int* __restrict__ bsums, int nb)
{
    __shared__ int s[1024];
    int t = threadIdx.x;
    int v = (t < nb) ? bsums[t] : 0;
    s[t] = v;
    __syncthreads();
    for (int off = 1; off < 1024; off <<= 1) {
        int add = (t >= off) ? s[t - off] : 0;
        __syncthreads();
        s[t] += add;
        __syncthreads();
    }
    if (t < nb) bsums[t] = s[t] - v;  // exclusive
}

__global__ void scanC_kernel(const int* __restrict__ counts, int N,
                             const int* __restrict__ bsums,
                             int* __restrict__ rowstart, int* __restrict__ cursor)
{
    __shared__ int s[256];
    int t = threadIdx.x;
    int base = blockIdx.x * 1024 + t * 4;
    int c[4];
    int sum = 0;
#pragma unroll
    for (int k = 0; k < 4; ++k) {
        int idx = base + k;
        c[k] = (idx < N) ? counts[idx] : 0;
        sum += c[k];
    }
    s[t] = sum;
    __syncthreads();
    for (int off = 1; off < 256; off <<= 1) {
        int add = (t >= off) ? s[t - off] : 0;
        __syncthreads();
        s[t] += add;
        __syncthreads();
    }
    int excl = s[t] - sum + bsums[blockIdx.x];
#pragma unroll
    for (int k = 0; k < 4; ++k) {
        int idx = base + k;
        if (idx < N) {
            rowstart[idx] = excl;
            cursor[idx]   = excl;
            excl += c[k];
        }
    }
}

__global__ void scatter_kernel(const int* __restrict__ src, const int* __restrict__ dst,
                               int E, int N, int* __restrict__ cursor,
                               int* __restrict__ esrc)
{
    int i = blockIdx.x * blockDim.x + threadIdx.x;
    if (i >= E + N) return;
    int s, d;
    if (i < E) { s = src[i]; d = dst[i]; }
    else       { s = i - E; d = s; }
    int pos = atomicAdd(&cursor[d], 1);
    esrc[pos] = s;
}

// ---------------------------------------------------------------------------
// Attention layer: per dst node, softmax(beta*cos) weighted sum of h[src].
// 16 lanes per node, lane = feature. No atomics, no segment_max
// (softmax shift-invariance: use constant shift |beta|).
// ---------------------------------------------------------------------------
__global__ __launch_bounds__(256) void agg_kernel(
    const float* __restrict__ h, const float* __restrict__ inv,
    const int* __restrict__ esrc, const int* __restrict__ rowstart,
    const int* __restrict__ counts, const float* __restrict__ beta_p,
    float* __restrict__ hout, float* __restrict__ invout, int N)
{
    int g = (blockIdx.x * blockDim.x + threadIdx.x) >> 4;  // node
    int j = threadIdx.x & 15;                              // feature
    if (g >= N) return;

    float beta  = *beta_p;
    float shift = fabsf(beta);
    float hd   = h[(size_t)g * HID + j];
    float invd = inv[g];
    int start = rowstart[g];
    int cnt   = counts[g];

    float denom = 0.f, acc = 0.f;
    for (int t = 0; t < cnt; ++t) {
        int s    = esrc[start + t];
        float hs = h[(size_t)s * HID + j];
        float p  = hs * hd;
        p += __shfl_xor(p, 1);
        p += __shfl_xor(p, 2);
        p += __shfl_xor(p, 4);
        p += __shfl_xor(p, 8);
        float cosv = p * invd * inv[s];
        float wgt  = __expf(beta * cosv - shift);
        denom += wgt;
        acc   += wgt * hs;
    }
    float o = acc / denom;
    hout[(size_t)g * HID + j] = o;

    float q = o * o;
    q += __shfl_xor(q, 1);
    q += __shfl_xor(q, 2);
    q += __shfl_xor(q, 4);
    q += __shfl_xor(q, 8);
    if (j == 0) invout[g] = 1.f / fmaxf(sqrtf(q), 1e-12f);
}

// ---------------------------------------------------------------------------
// K5: out = log_softmax(h2 @ W2 + b2). One wave per row, lane = class.
// ---------------------------------------------------------------------------
__global__ __launch_bounds__(256) void out_kernel(
    const float* __restrict__ h2, const float* __restrict__ W2,
    const float* __restrict__ b2, float* __restrict__ out, int N)
{
    int wave = (blockIdx.x * blockDim.x + threadIdx.x) >> 6;
    int lane = threadIdx.x & 63;
    if (wave >= N) return;

    float hv = (lane < HID) ? h2[(size_t)wave * HID + lane] : 0.f;
    float acc = b2[lane];
#pragma unroll
    for (int k = 0; k < HID; ++k) {
        float hk = __shfl(hv, k);
        acc += hk * W2[k * NCLS + lane];
    }
    // log-softmax over 64 lanes
    float m = acc;
    for (int off = 32; off > 0; off >>= 1) m = fmaxf(m, __shfl_xor(m, off));
    float e = __expf(acc - m);
    float ssum = e;
    for (int off = 32; off > 0; off >>= 1) ssum += __shfl_xor(ssum, off);
    out[(size_t)wave * NCLS + lane] = (acc - m) - __logf(ssum);
}

// ---------------------------------------------------------------------------
extern "C" void kernel_launch(void* const* d_in, const int* in_sizes, int n_in,
                              void* d_out, int out_size, void* d_ws, size_t ws_size,
                              hipStream_t stream)
{
    const float* x     = (const float*)d_in[0];
    const int*   eidx  = (const int*)d_in[1];
    const float* W1    = (const float*)d_in[2];
    const float* b1    = (const float*)d_in[3];
    const float* W2    = (const float*)d_in[4];
    const float* b2    = (const float*)d_in[5];
    const float* beta1 = (const float*)d_in[6];
    const float* beta2 = (const float*)d_in[7];

    int N = in_sizes[0] / F_IN;       // 100000
    int E = in_sizes[1] / 2;          // 3200000
    const int* src = eidx;
    const int* dst = eidx + E;
    float* out = (float*)d_out;

    // workspace carve-up (256B aligned)
    char* wptr = (char*)d_ws;
    auto alloc = [&](size_t bytes) -> char* {
        char* p = wptr;
        wptr += (bytes + 255) / 256 * 256;
        return p;
    };
    float* h0      = (float*)alloc((size_t)N * HID * 4);
    float* inv0    = (float*)alloc((size_t)N * 4);
    float* h1      = (float*)alloc((size_t)N * HID * 4);
    float* inv1    = (float*)alloc((size_t)N * 4);
    float* h2      = (float*)alloc((size_t)N * HID * 4);
    float* inv2    = (float*)alloc((size_t)N * 4);
    int*   counts  = (int*)alloc((size_t)N * 4);
    int*   rowstart= (int*)alloc((size_t)(N + 1) * 4);
    int*   cursor  = (int*)alloc((size_t)N * 4);
    int*   esrc    = (int*)alloc((size_t)(E + N) * 4);
    int*   bsums   = (int*)alloc(1024 * 4);

    int NB = (N + 1023) / 1024;       // scan blocks (98)
    int EV = E + N;                   // virtual edge count

    // CSR build
    hipMemsetAsync(counts, 0, (size_t)N * 4, stream);
    count_kernel<<<(EV + 255) / 256, 256, 0, stream>>>(dst, E, N, counts);
    scanA_kernel<<<NB, 256, 0, stream>>>(counts, N, bsums);
    scanB_kernel<<<1, 1024, 0, stream>>>(bsums, NB);
    scanC_kernel<<<NB, 256, 0, stream>>>(counts, N, bsums, rowstart, cursor);
    scatter_kernel<<<(EV + 255) / 256, 256, 0, stream>>>(src, dst, E, N, cursor, esrc);

    // h0 = relu(x@W1+b1), inv0
    int g1blocks = 512;
    gemm1_kernel<<<g1blocks, 256, 0, stream>>>(x, W1, b1, h0, inv0, N, g1blocks * 4);

    // two attention layers
    int aggBlocks = (N * HID + 255) / 256;
    agg_kernel<<<aggBlocks, 256, 0, stream>>>(h0, inv0, esrc, rowstart, counts, beta1,
                                              h1, inv1, N);
    agg_kernel<<<aggBlocks, 256, 0, stream>>>(h1, inv1, esrc, rowstart, counts, beta2,
                                              h2, inv2, N);

    // out = log_softmax(h2@W2+b2)
    out_kernel<<<(N * 64 + 255) / 256, 256, 0, stream>>>(h2, W2, b2, out, N);
}

// Round 2
// 717.543 us; speedup vs baseline: 1.4374x; 1.4374x over previous
//
#include <hip/hip_runtime.h>
#include <hip/hip_bf16.h>

#define F_IN 512
#define HID 16
#define NCLS 64
#define NBUCK_MAX 512     // LDS sizing; actual nbuck = ceil(N/256) = 391
#define EPB 8192          // edges per block in hist/partition

// ---------------------------------------------------------------------------
// K1: h0 = relu(x @ W1 + b1), inv0 = 1/max(||h0||,eps)
// One wave per row. W1 fragment register-resident: lane l owns k = l*8..l*8+7.
// ---------------------------------------------------------------------------
__global__ __launch_bounds__(256) void gemm1_kernel(
    const float* __restrict__ x, const float* __restrict__ W1,
    const float* __restrict__ b1, float* __restrict__ h0,
    float* __restrict__ inv0, int N, int totalWaves)
{
    int wid  = (blockIdx.x * blockDim.x + threadIdx.x) >> 6;
    int lane = threadIdx.x & 63;

    float4 w[8][4];
#pragma unroll
    for (int kk = 0; kk < 8; ++kk) {
        const float4* wp = (const float4*)(W1 + (lane * 8 + kk) * HID);
#pragma unroll
        for (int jj = 0; jj < 4; ++jj) w[kk][jj] = wp[jj];
    }

    for (int row = wid; row < N; row += totalWaves) {
        const float4* xp = (const float4*)(x + (size_t)row * F_IN + lane * 8);
        float4 xa = xp[0], xb = xp[1];
        float xs[8] = {xa.x, xa.y, xa.z, xa.w, xb.x, xb.y, xb.z, xb.w};
        float4 acc[4];
#pragma unroll
        for (int jj = 0; jj < 4; ++jj) acc[jj] = make_float4(0.f, 0.f, 0.f, 0.f);

#pragma unroll
        for (int kk = 0; kk < 8; ++kk) {
            float xv = xs[kk];
#pragma unroll
            for (int jj = 0; jj < 4; ++jj) {
                acc[jj].x += xv * w[kk][jj].x;
                acc[jj].y += xv * w[kk][jj].y;
                acc[jj].z += xv * w[kk][jj].z;
                acc[jj].w += xv * w[kk][jj].w;
            }
        }
        for (int off = 32; off > 0; off >>= 1) {
#pragma unroll
            for (int jj = 0; jj < 4; ++jj) {
                acc[jj].x += __shfl_xor(acc[jj].x, off);
                acc[jj].y += __shfl_xor(acc[jj].y, off);
                acc[jj].z += __shfl_xor(acc[jj].z, off);
                acc[jj].w += __shfl_xor(acc[jj].w, off);
            }
        }
        if (lane == 0) {
            float vals[16] = {acc[0].x, acc[0].y, acc[0].z, acc[0].w,
                              acc[1].x, acc[1].y, acc[1].z, acc[1].w,
                              acc[2].x, acc[2].y, acc[2].z, acc[2].w,
                              acc[3].x, acc[3].y, acc[3].z, acc[3].w};
            float ss = 0.f;
            float4 o[4];
            float* of = (float*)o;
#pragma unroll
            for (int j = 0; j < 16; ++j) {
                float v = fmaxf(vals[j] + b1[j], 0.f);
                of[j] = v;
                ss += v * v;
            }
            float4* hp = (float4*)(h0 + (size_t)row * HID);
#pragma unroll
            for (int jj = 0; jj < 4; ++jj) hp[jj] = o[jj];
            inv0[row] = 1.f / fmaxf(sqrtf(ss), 1e-12f);
        }
    }
}

// ---------------------------------------------------------------------------
// CSR build, pass 1: per-block LDS histogram of buckets (bucket = dst>>8).
// Virtual edge i in [0,E+N): i<E -> (src[i],dst[i]); else self-loop i-E.
// ---------------------------------------------------------------------------
__global__ __launch_bounds__(256) void hist1_kernel(
    const int* __restrict__ dst, int E, int EV, int nbuck,
    int* __restrict__ bucketCount)
{
    __shared__ int h[NBUCK_MAX];
    int tid = threadIdx.x;
    for (int j = tid; j < nbuck; j += 256) h[j] = 0;
    __syncthreads();
    int base = blockIdx.x * EPB;
    for (int k = 0; k < EPB / 256; ++k) {
        int i = base + k * 256 + tid;
        if (i < EV) {
            int d = (i < E) ? dst[i] : (i - E);
            atomicAdd(&h[d >> 8], 1);
        }
    }
    __syncthreads();
    for (int j = tid; j < nbuck; j += 256)
        if (h[j]) atomicAdd(&bucketCount[j], h[j]);
}

// ---------------------------------------------------------------------------
// CSR build, pass 2: single-WG exclusive scan of bucket counts.
// Writes bucketStart[0..nbuck] and initializes gCursor.
// ---------------------------------------------------------------------------
__global__ __launch_bounds__(512) void bucket_scan_kernel(
    const int* __restrict__ bucketCount, int nbuck,
    int* __restrict__ bucketStart, int* __restrict__ gCursor)
{
    __shared__ int s[512];
    int t = threadIdx.x;
    int v = (t < nbuck) ? bucketCount[t] : 0;
    s[t] = v;
    __syncthreads();
    for (int off = 1; off < 512; off <<= 1) {
        int add = (t >= off) ? s[t - off] : 0;
        __syncthreads();
        s[t] += add;
        __syncthreads();
    }
    int incl = s[t];
    if (t < nbuck) {
        bucketStart[t] = incl - v;
        gCursor[t]     = incl - v;
        if (t == nbuck - 1) bucketStart[nbuck] = incl;
    }
}

// ---------------------------------------------------------------------------
// CSR build, pass 3: partition edges into bucket regions of `staged`.
// Per-block: LDS histogram -> one global atomic per (block,bucket) to reserve
// a contiguous chunk -> chunked writes (temporal=spatial locality, ~no
// write amplification). staged entry packs src (17b) | dstLocal (8b) << 17.
// ---------------------------------------------------------------------------
__global__ __launch_bounds__(256) void partition_kernel(
    const int* __restrict__ src, const int* __restrict__ dst,
    int E, int EV, int nbuck, int* __restrict__ gCursor,
    unsigned* __restrict__ staged)
{
    __shared__ int h[NBUCK_MAX];
    __shared__ int gb[NBUCK_MAX];
    int tid = threadIdx.x;
    for (int j = tid; j < nbuck; j += 256) h[j] = 0;
    __syncthreads();

    unsigned pk[EPB / 256];
    int      bk[EPB / 256];
    int base = blockIdx.x * EPB;
#pragma unroll
    for (int k = 0; k < EPB / 256; ++k) {
        int i = base + k * 256 + tid;
        if (i < EV) {
            int s, d;
            if (i < E) { s = src[i]; d = dst[i]; }
            else       { s = i - E;  d = s; }
            bk[k] = d >> 8;
            pk[k] = (unsigned)s | ((unsigned)(d & 255) << 17);
            atomicAdd(&h[bk[k]], 1);
        } else {
            bk[k] = -1;
        }
    }
    __syncthreads();
    for (int j = tid; j < nbuck; j += 256) {
        int c = h[j];
        if (c) gb[j] = atomicAdd(&gCursor[j], c);
        h[j] = 0;  // reuse as local cursor
    }
    __syncthreads();
#pragma unroll
    for (int k = 0; k < EPB / 256; ++k) {
        if (bk[k] >= 0) {
            int ofs = atomicAdd(&h[bk[k]], 1);
            staged[gb[bk[k]] + ofs] = pk[k];
        }
    }
}

// ---------------------------------------------------------------------------
// CSR build, pass 4: one WG per bucket. LDS histogram + scan over the 256
// dsts of this bucket -> counts/rowstart; then scatter srcs into the
// bucket's esrc window (~34 KB, single-WG => single-XCD L2 locality).
// ---------------------------------------------------------------------------
__global__ __launch_bounds__(256) void build_csr_kernel(
    const unsigned* __restrict__ staged, const int* __restrict__ bucketStart,
    int* __restrict__ counts, int* __restrict__ rowstart,
    int* __restrict__ esrc, int N)
{
    __shared__ int hist[256];
    __shared__ int s[256];
    __shared__ int cur[256];
    int b   = blockIdx.x;
    int tid = threadIdx.x;
    int start = bucketStart[b];
    int end   = bucketStart[b + 1];

    hist[tid] = 0;
    __syncthreads();
    for (int i = start + tid; i < end; i += 256)
        atomicAdd(&hist[(staged[i] >> 17) & 255], 1);
    __syncthreads();

    int v = hist[tid];
    s[tid] = v;
    __syncthreads();
    for (int off = 1; off < 256; off <<= 1) {
        int add = (tid >= off) ? s[tid - off] : 0;
        __syncthreads();
        s[tid] += add;
        __syncthreads();
    }
    int excl = s[tid] - v;
    int dstg = b * 256 + tid;
    if (dstg < N) {
        counts[dstg]   = v;
        rowstart[dstg] = start + excl;
    }
    cur[tid] = start + excl;
    __syncthreads();

    for (int i = start + tid; i < end; i += 256) {
        unsigned pk = staged[i];
        int dl  = (pk >> 17) & 255;
        int pos = atomicAdd(&cur[dl], 1);
        esrc[pos] = (int)(pk & 0x1FFFFu);
    }
}

// ---------------------------------------------------------------------------
// Attention layer: per dst node, softmax(beta*cos) weighted sum of h[src].
// 16 lanes per node, lane = feature. No atomics, no segment_max
// (softmax shift-invariance: constant shift |beta| since cos in [-1,1]).
// ---------------------------------------------------------------------------
__global__ __launch_bounds__(256) void agg_kernel(
    const float* __restrict__ h, const float* __restrict__ inv,
    const int* __restrict__ esrc, const int* __restrict__ rowstart,
    const int* __restrict__ counts, const float* __restrict__ beta_p,
    float* __restrict__ hout, float* __restrict__ invout, int N)
{
    int g = (blockIdx.x * blockDim.x + threadIdx.x) >> 4;
    int j = threadIdx.x & 15;
    if (g >= N) return;

    float beta  = *beta_p;
    float shift = fabsf(beta);
    float hd   = h[(size_t)g * HID + j];
    float invd = inv[g];
    int start = rowstart[g];
    int cnt   = counts[g];

    float denom = 0.f, acc = 0.f;
    for (int t = 0; t < cnt; ++t) {
        int sidx = esrc[start + t];
        float hs = h[(size_t)sidx * HID + j];
        float p  = hs * hd;
        p += __shfl_xor(p, 1);
        p += __shfl_xor(p, 2);
        p += __shfl_xor(p, 4);
        p += __shfl_xor(p, 8);
        float cosv = p * invd * inv[sidx];
        float wgt  = __expf(beta * cosv - shift);
        denom += wgt;
        acc   += wgt * hs;
    }
    float o = acc / denom;
    hout[(size_t)g * HID + j] = o;

    float q = o * o;
    q += __shfl_xor(q, 1);
    q += __shfl_xor(q, 2);
    q += __shfl_xor(q, 4);
    q += __shfl_xor(q, 8);
    if (j == 0) invout[g] = 1.f / fmaxf(sqrtf(q), 1e-12f);
}

// ---------------------------------------------------------------------------
// K5: out = log_softmax(h2 @ W2 + b2). One wave per row, lane = class.
// ---------------------------------------------------------------------------
__global__ __launch_bounds__(256) void out_kernel(
    const float* __restrict__ h2, const float* __restrict__ W2,
    const float* __restrict__ b2, float* __restrict__ out, int N)
{
    int wave = (blockIdx.x * blockDim.x + threadIdx.x) >> 6;
    int lane = threadIdx.x & 63;
    if (wave >= N) return;

    float hv = (lane < HID) ? h2[(size_t)wave * HID + lane] : 0.f;
    float acc = b2[lane];
#pragma unroll
    for (int k = 0; k < HID; ++k) {
        float hk = __shfl(hv, k);
        acc += hk * W2[k * NCLS + lane];
    }
    float m = acc;
    for (int off = 32; off > 0; off >>= 1) m = fmaxf(m, __shfl_xor(m, off));
    float e = __expf(acc - m);
    float ssum = e;
    for (int off = 32; off > 0; off >>= 1) ssum += __shfl_xor(ssum, off);
    out[(size_t)wave * NCLS + lane] = (acc - m) - __logf(ssum);
}

// ---------------------------------------------------------------------------
extern "C" void kernel_launch(void* const* d_in, const int* in_sizes, int n_in,
                              void* d_out, int out_size, void* d_ws, size_t ws_size,
                              hipStream_t stream)
{
    const float* x     = (const float*)d_in[0];
    const int*   eidx  = (const int*)d_in[1];
    const float* W1    = (const float*)d_in[2];
    const float* b1    = (const float*)d_in[3];
    const float* W2    = (const float*)d_in[4];
    const float* b2    = (const float*)d_in[5];
    const float* beta1 = (const float*)d_in[6];
    const float* beta2 = (const float*)d_in[7];

    int N = in_sizes[0] / F_IN;       // 100000
    int E = in_sizes[1] / 2;          // 3200000
    const int* src = eidx;
    const int* dst = eidx + E;
    float* out = (float*)d_out;

    int EV    = E + N;                // virtual edges (incl. self-loops)
    int nbuck = (N + 255) / 256;      // 391

    char* wptr = (char*)d_ws;
    auto alloc = [&](size_t bytes) -> char* {
        char* p = wptr;
        wptr += (bytes + 255) / 256 * 256;
        return p;
    };
    float*    h0       = (float*)alloc((size_t)N * HID * 4);
    float*    inv0     = (float*)alloc((size_t)N * 4);
    float*    h1       = (float*)alloc((size_t)N * HID * 4);
    float*    inv1     = (float*)alloc((size_t)N * 4);
    float*    h2       = (float*)alloc((size_t)N * HID * 4);
    float*    inv2     = (float*)alloc((size_t)N * 4);
    int*      counts   = (int*)alloc((size_t)N * 4);
    int*      rowstart = (int*)alloc((size_t)(N + 1) * 4);
    int*      esrc     = (int*)alloc((size_t)EV * 4);
    unsigned* staged   = (unsigned*)alloc((size_t)EV * 4);
    int*      bucketCount = (int*)alloc((size_t)(nbuck + 1) * 4);
    int*      bucketStart = (int*)alloc((size_t)(nbuck + 1) * 4);
    int*      gCursor     = (int*)alloc((size_t)nbuck * 4);

    int ebBlocks = (EV + EPB - 1) / EPB;  // 403

    // CSR build (counting sort, write-locality aware)
    hipMemsetAsync(bucketCount, 0, (size_t)nbuck * 4, stream);
    hist1_kernel<<<ebBlocks, 256, 0, stream>>>(dst, E, EV, nbuck, bucketCount);
    bucket_scan_kernel<<<1, 512, 0, stream>>>(bucketCount, nbuck, bucketStart, gCursor);
    partition_kernel<<<ebBlocks, 256, 0, stream>>>(src, dst, E, EV, nbuck, gCursor, staged);
    build_csr_kernel<<<nbuck, 256, 0, stream>>>(staged, bucketStart, counts, rowstart,
                                                esrc, N);

    // h0 = relu(x@W1+b1), inv0   (overlaps CSR build: independent)
    int g1blocks = 512;
    gemm1_kernel<<<g1blocks, 256, 0, stream>>>(x, W1, b1, h0, inv0, N, g1blocks * 4);

    // two attention layers
    int aggBlocks = (N * HID + 255) / 256;
    agg_kernel<<<aggBlocks, 256, 0, stream>>>(h0, inv0, esrc, rowstart, counts, beta1,
                                              h1, inv1, N);
    agg_kernel<<<aggBlocks, 256, 0, stream>>>(h1, inv1, esrc, rowstart, counts, beta2,
                                              h2, inv2, N);

    // out = log_softmax(h2@W2+b2)
    out_kernel<<<(N * 64 + 255) / 256, 256, 0, stream>>>(h2, W2, b2, out, N);
}